// Round 1
// baseline (415.994 us; speedup 1.0000x reference)
//
#include <hip/hip_runtime.h>
#include <stdint.h>

#define H_ 192
#define W_ 192
#define C_ 64
#define EPS_F 1e-8f
#define TILE 16
#define CHUNK 64
#define NSLICE 8

// Output layout (floats), concatenated in reference return order:
// feats (H*W*C) | p2f (H*W) | zbuf (H*W) | bary (H*W*3) | dists (H*W)
#define OFF_FEATS 0
#define OFF_P2F   (H_*W_*C_)
#define OFF_ZBUF  (OFF_P2F + H_*W_)
#define OFF_BARY  (OFF_ZBUF + H_*W_)
#define OFF_DIST  (OFF_BARY + H_*W_*3)

// IEEE-exact ops (block FMA contraction; match numpy float32 op-for-op)
__device__ __forceinline__ float xm(float a, float b){ return __fmul_rn(a,b); }
__device__ __forceinline__ float xa(float a, float b){ return __fadd_rn(a,b); }
__device__ __forceinline__ float xsb(float a, float b){ return __fsub_rn(a,b); }
__device__ __forceinline__ float xd(float a, float b){ return __fdiv_rn(a,b); }

// 1 - (2*i + 1)/dim, exactly as reference computes pixel coords
__device__ __forceinline__ float pixcoord(int i, float dim){
    float t = xa(xm(2.0f, (float)i), 1.0f);
    return xsb(1.0f, xd(t, dim));
}

__global__ void k_verts(const float* __restrict__ pos, const float* __restrict__ K,
                        const float* __restrict__ RT, float* __restrict__ verts, int V){
    int v = blockIdx.x*blockDim.x + threadIdx.x;
    if (v >= V) return;
    float p0 = pos[3*v+0], p1 = pos[3*v+1], p2 = pos[3*v+2];
    const float sgn[3] = {-1.f, -1.f, 1.f};
    float vv[3];
    #pragma unroll
    for (int j=0;j<3;j++){
        // R_p[i][j] = R[j][i]*sign[j]; v_view[j] = sum_i pos[i]*R_p[i][j] + t[j]*sign[j]
        float rp0 = xm(RT[j*4+0], sgn[j]);
        float rp1 = xm(RT[j*4+1], sgn[j]);
        float rp2 = xm(RT[j*4+2], sgn[j]);
        float s = xa(xa(xm(p0,rp0), xm(p1,rp1)), xm(p2,rp2));
        vv[j] = xa(s, xm(RT[j*4+3], sgn[j]));
    }
    float z = vv[2];
    const float scale = 96.0f;           // min(H,W)/2
    float fx = xd(K[0], scale);          // K[0][0]/scale
    float fy = xd(K[4], scale);          // K[1][1]/scale
    float p0x = -xd(xsb(K[2], 96.0f), scale);  // -(K02 - W/2)/scale
    float p0y = -xd(xsb(K[5], 96.0f), scale);
    float xn = xa(xd(xm(fx, vv[0]), z), p0x);
    float yn = xa(xd(xm(fy, vv[1]), z), p0y);
    verts[4*v+0] = xn; verts[4*v+1] = yn; verts[4*v+2] = z; verts[4*v+3] = 0.f;
}

__global__ void k_faces(const int* __restrict__ faces, const float* __restrict__ verts,
                        float* __restrict__ rec, int Fn){
    int f = blockIdx.x*blockDim.x + threadIdx.x;
    if (f >= Fn) return;
    int i0 = faces[3*f+0], i1 = faces[3*f+1], i2 = faces[3*f+2];
    float x0=verts[4*i0+0], y0=verts[4*i0+1], z0=verts[4*i0+2];
    float x1=verts[4*i1+0], y1=verts[4*i1+1], z1=verts[4*i1+2];
    float x2=verts[4*i2+0], y2=verts[4*i2+1], z2=verts[4*i2+2];
    float area = xsb(xm(xsb(x1,x0), xsb(y2,y0)), xm(xsb(y1,y0), xsb(x2,x0)));
    bool ok = (area > EPS_F) && (z0 > 0.f) && (z1 > 0.f) && (z2 > 0.f);
    float inv_area = ok ? xd(1.0f, area) : 0.0f;
    float xmin, xmax, ymin, ymax;
    if (ok){
        xmin = fminf(x0, fminf(x1, x2)) - 1e-4f;
        xmax = fmaxf(x0, fmaxf(x1, x2)) + 1e-4f;
        ymin = fminf(y0, fminf(y1, y2)) - 1e-4f;
        ymax = fmaxf(y0, fmaxf(y1, y2)) + 1e-4f;
    } else {
        // empty bbox -> uniformly culled everywhere
        xmin = INFINITY; xmax = -INFINITY; ymin = INFINITY; ymax = -INFINITY;
    }
    float* r = rec + (size_t)f*16;
    r[0]=x0; r[1]=y0; r[2]=x1; r[3]=y1; r[4]=x2; r[5]=y2;
    r[6]=z0; r[7]=z1; r[8]=z2; r[9]=inv_area;
    r[10]=xmin; r[11]=xmax; r[12]=ymin; r[13]=ymax; r[14]=0.f; r[15]=0.f;
}

__global__ __launch_bounds__(256) void k_raster(const float* __restrict__ rec,
        unsigned long long* __restrict__ keys, int Fn){
    __shared__ float lds[CHUNK*16];
    int ix = blockIdx.x*TILE + threadIdx.x;
    int iy = blockIdx.y*TILE + threadIdx.y;
    int pix = iy*W_ + ix;
    float px = pixcoord(ix, (float)W_);
    float py = pixcoord(iy, (float)H_);
    // tile bounds in NDC (px decreasing with ix) -- block-uniform
    float tx_hi = pixcoord(blockIdx.x*TILE,          (float)W_);
    float tx_lo = pixcoord(blockIdx.x*TILE + TILE-1, (float)W_);
    float ty_hi = pixcoord(blockIdx.y*TILE,          (float)H_);
    float ty_lo = pixcoord(blockIdx.y*TILE + TILE-1, (float)H_);
    int perSlice = Fn / NSLICE;
    int f0 = blockIdx.z * perSlice;
    int f1 = f0 + perSlice;
    int tid = threadIdx.y*TILE + threadIdx.x;

    float zbest = INFINITY;
    int fbest = -1;

    for (int base = f0; base < f1; base += CHUNK){
        __syncthreads();
        const float4* src = (const float4*)(rec + (size_t)base*16);
        ((float4*)lds)[tid] = src[tid];   // 256 float4 = 64 faces * 16 floats
        __syncthreads();
        #pragma unroll 4
        for (int j=0; j<CHUNK; j++){
            const float* r = lds + j*16;
            float xmin=r[10], xmax=r[11], ymin=r[12], ymax=r[13];
            // block-uniform cull (scalar branch: condition depends on block only)
            if (xmin > tx_hi || xmax < tx_lo || ymin > ty_hi || ymax < ty_lo) continue;
            float x0=r[0], y0=r[1], x1=r[2], y1=r[3], x2=r[4], y2=r[5];
            float z0=r[6], z1=r[7], z2=r[8], ia=r[9];
            float w0 = xm(xsb(xm(xsb(x1,px),xsb(y2,py)), xm(xsb(y1,py),xsb(x2,px))), ia);
            float w1 = xm(xsb(xm(xsb(x2,px),xsb(y0,py)), xm(xsb(y2,py),xsb(x0,px))), ia);
            float w2 = xm(xsb(xm(xsb(x0,px),xsb(y1,py)), xm(xsb(y0,py),xsb(x1,px))), ia);
            if (w0 >= 0.f && w1 >= 0.f && w2 >= 0.f){
                float l0 = xm(xm(w0,z1),z2);
                float l1 = xm(xm(z0,w1),z2);
                float l2 = xm(xm(z0,z1),w2);
                float s  = xa(xa(l0,l1),l2);
                float dn = (s == 0.f) ? 1.0f : s;
                float b0 = fmaxf(xd(l0,dn), 0.f);
                float b1 = fmaxf(xd(l1,dn), 0.f);
                float b2 = fmaxf(xd(l2,dn), 0.f);
                float bs = fmaxf(xa(xa(b0,b1),b2), EPS_F);
                b0 = xd(b0,bs); b1 = xd(b1,bs); b2 = xd(b2,bs);
                float zp = xa(xa(xm(b0,z0),xm(b1,z1)),xm(b2,z2));
                if (zp < zbest){ zbest = zp; fbest = base + j; }
            }
        }
    }
    if (fbest >= 0){
        unsigned long long key =
            (((unsigned long long)__float_as_uint(zbest)) << 32) | (unsigned)fbest;
        atomicMin(&keys[pix], key);
    }
}

__global__ void k_resolve(const unsigned long long* __restrict__ keys,
        const float* __restrict__ rec, float* __restrict__ out){
    int pix = blockIdx.x*blockDim.x + threadIdx.x;
    if (pix >= H_*W_) return;
    float* p2f  = out + OFF_P2F;
    float* zbuf = out + OFF_ZBUF;
    float* bary = out + OFF_BARY;
    float* dist = out + OFF_DIST;
    unsigned long long key = keys[pix];
    if (key == 0xFFFFFFFFFFFFFFFFULL){
        p2f[pix] = -1.0f; zbuf[pix] = -1.0f;
        bary[3*pix+0] = -1.0f; bary[3*pix+1] = -1.0f; bary[3*pix+2] = -1.0f;
        dist[pix] = -1.0f;
        return;
    }
    int f = (int)(key & 0xFFFFFFFFu);
    float z = __uint_as_float((unsigned)(key >> 32));
    int ix = pix % W_, iy = pix / W_;
    float px = pixcoord(ix, (float)W_);
    float py = pixcoord(iy, (float)H_);
    const float* r = rec + (size_t)f*16;
    float x0=r[0], y0=r[1], x1=r[2], y1=r[3], x2=r[4], y2=r[5];
    float z0=r[6], z1=r[7], z2=r[8], ia=r[9];
    float w0 = xm(xsb(xm(xsb(x1,px),xsb(y2,py)), xm(xsb(y1,py),xsb(x2,px))), ia);
    float w1 = xm(xsb(xm(xsb(x2,px),xsb(y0,py)), xm(xsb(y2,py),xsb(x0,px))), ia);
    float w2 = xm(xsb(xm(xsb(x0,px),xsb(y1,py)), xm(xsb(y0,py),xsb(x1,px))), ia);
    float l0 = xm(xm(w0,z1),z2);
    float l1 = xm(xm(z0,w1),z2);
    float l2 = xm(xm(z0,z1),w2);
    float s  = xa(xa(l0,l1),l2);
    float dn = (s == 0.f) ? 1.0f : s;
    float b0 = fmaxf(xd(l0,dn), 0.f);
    float b1 = fmaxf(xd(l1,dn), 0.f);
    float b2 = fmaxf(xd(l2,dn), 0.f);
    float bs = fmaxf(xa(xa(b0,b1),b2), EPS_F);
    b0 = xd(b0,bs); b1 = xd(b1,bs); b2 = xd(b2,bs);
    p2f[pix] = (float)f;          // B=1 -> face offset 0
    zbuf[pix] = z;
    bary[3*pix+0] = b0; bary[3*pix+1] = b1; bary[3*pix+2] = b2;
    dist[pix] = 0.0f;
}

__global__ __launch_bounds__(256) void k_shade(const float* __restrict__ feats,
        const int* __restrict__ faces, float* __restrict__ out){
    int local = threadIdx.x >> 6;          // 4 pixels per block
    int c = threadIdx.x & 63;              // 64 channels
    int pix = blockIdx.x*4 + local;
    const float* p2f  = out + OFF_P2F;
    const float* bary = out + OFF_BARY;
    float fv = p2f[pix];
    float res = 0.0f;
    if (fv >= 0.0f){
        int f = (int)fv;
        int i0 = faces[3*f+0], i1 = faces[3*f+1], i2 = faces[3*f+2];
        float b0 = bary[3*pix+0], b1 = bary[3*pix+1], b2 = bary[3*pix+2];
        res = xa(xa(xm(b0, feats[i0*C_ + c]), xm(b1, feats[i1*C_ + c])),
                 xm(b2, feats[i2*C_ + c]));
    }
    out[OFF_FEATS + pix*C_ + c] = res;
}

extern "C" void kernel_launch(void* const* d_in, const int* in_sizes, int n_in,
                              void* d_out, int out_size, void* d_ws, size_t ws_size,
                              hipStream_t stream) {
    const float* positions = (const float*)d_in[0];
    const float* features  = (const float*)d_in[1];
    const int*   faces     = (const int*)  d_in[2];
    const float* K         = (const float*)d_in[3];
    const float* RT        = (const float*)d_in[4];
    int V  = in_sizes[0] / 3;   // 8192
    int Fn = in_sizes[2] / 3;   // 16384

    float* verts = (float*)d_ws;                     // V*4 floats
    float* rec   = verts + (size_t)V*4;              // Fn*16 floats
    unsigned long long* keys = (unsigned long long*)(rec + (size_t)Fn*16);

    hipMemsetAsync(keys, 0xFF, (size_t)H_*W_*sizeof(unsigned long long), stream);
    k_verts<<<(V+255)/256, 256, 0, stream>>>(positions, K, RT, verts, V);
    k_faces<<<(Fn+255)/256, 256, 0, stream>>>(faces, verts, rec, Fn);
    dim3 rg(W_/TILE, H_/TILE, NSLICE);
    k_raster<<<rg, dim3(TILE, TILE, 1), 0, stream>>>(rec, keys, Fn);
    k_resolve<<<(H_*W_+255)/256, 256, 0, stream>>>(keys, rec, (float*)d_out);
    k_shade<<<(H_*W_)/4, 256, 0, stream>>>(features, faces, (float*)d_out);
}

// Round 2
// 177.232 us; speedup vs baseline: 2.3472x; 2.3472x over previous
//
#include <hip/hip_runtime.h>
#include <stdint.h>

#define H_ 192
#define W_ 192
#define C_ 64
#define EPS_F 1e-8f
#define TILE 16
#define CHUNK 256
#define NSLICE 16

typedef unsigned long long ull;

// Output layout (floats), concatenated in reference return order:
// feats (H*W*C) | p2f (H*W) | zbuf (H*W) | bary (H*W*3) | dists (H*W)
#define OFF_FEATS 0
#define OFF_P2F   (H_*W_*C_)
#define OFF_ZBUF  (OFF_P2F + H_*W_)
#define OFF_BARY  (OFF_ZBUF + H_*W_)
#define OFF_DIST  (OFF_BARY + H_*W_*3)

// IEEE-exact ops (block FMA contraction; match numpy float32 op-for-op)
__device__ __forceinline__ float xm(float a, float b){ return __fmul_rn(a,b); }
__device__ __forceinline__ float xa(float a, float b){ return __fadd_rn(a,b); }
__device__ __forceinline__ float xsb(float a, float b){ return __fsub_rn(a,b); }
__device__ __forceinline__ float xd(float a, float b){ return __fdiv_rn(a,b); }

__device__ __forceinline__ float pixcoord(int i, float dim){
    float t = xa(xm(2.0f, (float)i), 1.0f);
    return xsb(1.0f, xd(t, dim));
}

// Fused: key-buffer init + vertex transform
__global__ void k_init(const float* __restrict__ pos, const float* __restrict__ K,
                       const float* __restrict__ RT, float* __restrict__ verts,
                       ull* __restrict__ keys, int V){
    int i = blockIdx.x*blockDim.x + threadIdx.x;
    if (i < H_*W_) keys[i] = 0xFFFFFFFFFFFFFFFFULL;
    if (i >= V) return;
    float p0 = pos[3*i+0], p1 = pos[3*i+1], p2 = pos[3*i+2];
    const float sgn[3] = {-1.f, -1.f, 1.f};
    float vv[3];
    #pragma unroll
    for (int j=0;j<3;j++){
        float rp0 = xm(RT[j*4+0], sgn[j]);
        float rp1 = xm(RT[j*4+1], sgn[j]);
        float rp2 = xm(RT[j*4+2], sgn[j]);
        float s = xa(xa(xm(p0,rp0), xm(p1,rp1)), xm(p2,rp2));
        vv[j] = xa(s, xm(RT[j*4+3], sgn[j]));
    }
    float z = vv[2];
    const float scale = 96.0f;
    float fx = xd(K[0], scale);
    float fy = xd(K[4], scale);
    float p0x = -xd(xsb(K[2], 96.0f), scale);
    float p0y = -xd(xsb(K[5], 96.0f), scale);
    float xn = xa(xd(xm(fx, vv[0]), z), p0x);
    float yn = xa(xd(xm(fy, vv[1]), z), p0y);
    verts[4*i+0] = xn; verts[4*i+1] = yn; verts[4*i+2] = z; verts[4*i+3] = 0.f;
}

// Face record (16 floats):
// q0: x0,y0,x1,y1 | q1: x2,y2,z0,z1 | q2: z2,ia,zmin,0 | q3: xmin,xmax,ymin,ymax
__global__ void k_faces(const int* __restrict__ faces, const float* __restrict__ verts,
                        float* __restrict__ rec, int Fn){
    int f = blockIdx.x*blockDim.x + threadIdx.x;
    if (f >= Fn) return;
    int i0 = faces[3*f+0], i1 = faces[3*f+1], i2 = faces[3*f+2];
    float x0=verts[4*i0+0], y0=verts[4*i0+1], z0=verts[4*i0+2];
    float x1=verts[4*i1+0], y1=verts[4*i1+1], z1=verts[4*i1+2];
    float x2=verts[4*i2+0], y2=verts[4*i2+1], z2=verts[4*i2+2];
    float area = xsb(xm(xsb(x1,x0), xsb(y2,y0)), xm(xsb(y1,y0), xsb(x2,x0)));
    bool ok = (area > EPS_F) && (z0 > 0.f) && (z1 > 0.f) && (z2 > 0.f);
    float inv_area = ok ? xd(1.0f, area) : 0.0f;
    float xmn, xmx, ymn, ymx, zmn;
    if (ok){
        xmn = fminf(x0, fminf(x1, x2)) - 1e-4f;
        xmx = fmaxf(x0, fmaxf(x1, x2)) + 1e-4f;
        ymn = fminf(y0, fminf(y1, y2)) - 1e-4f;
        ymx = fmaxf(y0, fmaxf(y1, y2)) + 1e-4f;
        zmn = fminf(z0, fminf(z1, z2));
    } else {
        xmn = INFINITY; xmx = -INFINITY; ymn = INFINITY; ymx = -INFINITY;
        zmn = INFINITY;
    }
    float4* q = (float4*)(rec + (size_t)f*16);
    q[0] = make_float4(x0, y0, x1, y1);
    q[1] = make_float4(x2, y2, z0, z1);
    q[2] = make_float4(z2, inv_area, zmn, 0.f);
    q[3] = make_float4(xmn, xmx, ymn, ymx);
}

__global__ __launch_bounds__(256) void k_raster(const float* __restrict__ rec,
        ull* __restrict__ keys, int Fn){
    __shared__ float lds[CHUNK*12];   // 12 floats per face
    __shared__ float zl[CHUNK];       // zmin of survivors, compacted
    __shared__ int   slist[CHUNK];    // survivor face-local indices, compacted
    __shared__ int   wcnt[4];
    int tid = threadIdx.x;
    int ix = blockIdx.x*TILE + (tid & 15);
    int iy = blockIdx.y*TILE + (tid >> 4);
    int pix = iy*W_ + ix;
    float px = pixcoord(ix, (float)W_);
    float py = pixcoord(iy, (float)H_);
    float tx_hi = pixcoord(blockIdx.x*TILE,          (float)W_);
    float tx_lo = pixcoord(blockIdx.x*TILE + TILE-1, (float)W_);
    float ty_hi = pixcoord(blockIdx.y*TILE,          (float)H_);
    float ty_lo = pixcoord(blockIdx.y*TILE + TILE-1, (float)H_);
    int perSlice = Fn / NSLICE;
    int f0 = blockIdx.z * perSlice;
    int f1 = f0 + perSlice;
    int lane = tid & 63, wv = tid >> 6;

    float zbest = INFINITY;
    int fbest = -1;

    for (int base = f0; base < f1; base += CHUNK){
        __syncthreads();   // protect lds/slist/zl from previous iteration readers
        const float4* g = (const float4*)(rec + (size_t)(base + tid)*16);
        float4 q0 = g[0], q1 = g[1], q2 = g[2], q3 = g[3];
        // bbox-vs-tile overlap; dead faces have empty bbox -> rejected
        bool keep = (q3.x <= tx_hi) && (q3.y >= tx_lo) && (q3.z <= ty_hi) && (q3.w >= ty_lo);
        float4* l = (float4*)(lds + tid*12);
        l[0] = q0; l[1] = q1; l[2] = q2;
        ull m = __ballot(keep);
        if (lane == 0) wcnt[wv] = __popcll(m);
        __syncthreads();
        int basecnt = 0;
        #pragma unroll
        for (int w2 = 0; w2 < 4; ++w2) if (w2 < wv) basecnt += wcnt[w2];
        if (keep){
            int pos = basecnt + __popcll(m & ((1ULL << lane) - 1ULL));
            slist[pos] = tid;
            zl[pos] = q2.z;   // zmin
        }
        int nsurv = wcnt[0] + wcnt[1] + wcnt[2] + wcnt[3];
        __syncthreads();

        for (int k = 0; k < nsurv; k++){
            float zminf = zl[k];
            // conservative depth pre-check: zpix >= zmin*(1-1e-6), margin 0.999
            if (!(xm(zminf, 0.999f) < zbest)) continue;
            int j = slist[k];
            const float* r = lds + j*12;
            float x0=r[0], y0=r[1], x1=r[2], y1=r[3], x2=r[4], y2=r[5];
            float dx0=xsb(x0,px), dx1=xsb(x1,px), dx2=xsb(x2,px);
            float dy0=xsb(y0,py), dy1=xsb(y1,py), dy2=xsb(y2,py);
            // edge functions: sign(e_i) == sign(w_i) since ia>0 (mul is sign-preserving)
            float e0 = xsb(xm(dx1,dy2), xm(dy1,dx2));
            float e1 = xsb(xm(dx2,dy0), xm(dy2,dx0));
            float e2 = xsb(xm(dx0,dy1), xm(dy0,dx1));
            if (e0 >= 0.f && e1 >= 0.f && e2 >= 0.f){
                float z0=r[6], z1=r[7], z2=r[8], ia=r[9];
                float w0 = xm(e0, ia), w1 = xm(e1, ia), w2 = xm(e2, ia);
                float l0 = xm(xm(w0,z1),z2);
                float l1 = xm(xm(z0,w1),z2);
                float l2 = xm(xm(z0,z1),w2);
                float s  = xa(xa(l0,l1),l2);
                float dn = (s == 0.f) ? 1.0f : s;
                float b0 = fmaxf(xd(l0,dn), 0.f);
                float b1 = fmaxf(xd(l1,dn), 0.f);
                float b2 = fmaxf(xd(l2,dn), 0.f);
                float bs = fmaxf(xa(xa(b0,b1),b2), EPS_F);
                b0 = xd(b0,bs); b1 = xd(b1,bs); b2 = xd(b2,bs);
                float zp = xa(xa(xm(b0,z0),xm(b1,z1)),xm(b2,z2));
                if (zp < zbest){ zbest = zp; fbest = base + j; }
            }
        }
    }
    if (fbest >= 0){
        ull key = (((ull)__float_as_uint(zbest)) << 32) | (unsigned)fbest;
        atomicMin(&keys[pix], key);
    }
}

// Fused resolve + shade: 64 lanes per pixel (lane = channel), 4 pixels/block
__global__ __launch_bounds__(256) void k_post(const ull* __restrict__ keys,
        const float* __restrict__ rec, const float* __restrict__ feats,
        const int* __restrict__ faces, float* __restrict__ out){
    int grp = threadIdx.x >> 6;
    int c = threadIdx.x & 63;
    int pix = blockIdx.x*4 + grp;
    float* p2f  = out + OFF_P2F;
    float* zbuf = out + OFF_ZBUF;
    float* bary = out + OFF_BARY;
    float* dist = out + OFF_DIST;
    ull key = keys[pix];
    if (key == 0xFFFFFFFFFFFFFFFFULL){
        out[OFF_FEATS + pix*C_ + c] = 0.0f;
        if (c == 0){
            p2f[pix] = -1.0f; zbuf[pix] = -1.0f; dist[pix] = -1.0f;
        }
        if (c < 3) bary[3*pix+c] = -1.0f;
        return;
    }
    int f = (int)(key & 0xFFFFFFFFu);
    float z = __uint_as_float((unsigned)(key >> 32));
    int ix = pix % W_, iy = pix / W_;
    float px = pixcoord(ix, (float)W_);
    float py = pixcoord(iy, (float)H_);
    const float* r = rec + (size_t)f*16;
    float x0=r[0], y0=r[1], x1=r[2], y1=r[3], x2=r[4], y2=r[5];
    float z0=r[6], z1=r[7], z2=r[8], ia=r[9];
    float w0 = xm(xsb(xm(xsb(x1,px),xsb(y2,py)), xm(xsb(y1,py),xsb(x2,px))), ia);
    float w1 = xm(xsb(xm(xsb(x2,px),xsb(y0,py)), xm(xsb(y2,py),xsb(x0,px))), ia);
    float w2 = xm(xsb(xm(xsb(x0,px),xsb(y1,py)), xm(xsb(y0,py),xsb(x1,px))), ia);
    float l0 = xm(xm(w0,z1),z2);
    float l1 = xm(xm(z0,w1),z2);
    float l2 = xm(xm(z0,z1),w2);
    float s  = xa(xa(l0,l1),l2);
    float dn = (s == 0.f) ? 1.0f : s;
    float b0 = fmaxf(xd(l0,dn), 0.f);
    float b1 = fmaxf(xd(l1,dn), 0.f);
    float b2 = fmaxf(xd(l2,dn), 0.f);
    float bs = fmaxf(xa(xa(b0,b1),b2), EPS_F);
    b0 = xd(b0,bs); b1 = xd(b1,bs); b2 = xd(b2,bs);
    int i0 = faces[3*f+0], i1 = faces[3*f+1], i2 = faces[3*f+2];
    float res = xa(xa(xm(b0, feats[i0*C_ + c]), xm(b1, feats[i1*C_ + c])),
                   xm(b2, feats[i2*C_ + c]));
    out[OFF_FEATS + pix*C_ + c] = res;
    if (c == 0){
        p2f[pix] = (float)f; zbuf[pix] = z; dist[pix] = 0.0f;
    }
    if (c < 3){
        float bb = (c == 0) ? b0 : ((c == 1) ? b1 : b2);
        bary[3*pix+c] = bb;
    }
}

extern "C" void kernel_launch(void* const* d_in, const int* in_sizes, int n_in,
                              void* d_out, int out_size, void* d_ws, size_t ws_size,
                              hipStream_t stream) {
    const float* positions = (const float*)d_in[0];
    const float* features  = (const float*)d_in[1];
    const int*   faces     = (const int*)  d_in[2];
    const float* K         = (const float*)d_in[3];
    const float* RT        = (const float*)d_in[4];
    int V  = in_sizes[0] / 3;   // 8192
    int Fn = in_sizes[2] / 3;   // 16384

    float* verts = (float*)d_ws;                     // V*4 floats
    float* rec   = verts + (size_t)V*4;              // Fn*16 floats
    ull*   keys  = (ull*)(rec + (size_t)Fn*16);      // H*W keys

    int initN = H_*W_;  // covers keys (36864) and verts (8192)
    k_init<<<(initN+255)/256, 256, 0, stream>>>(positions, K, RT, verts, keys, V);
    k_faces<<<(Fn+255)/256, 256, 0, stream>>>(faces, verts, rec, Fn);
    dim3 rg(W_/TILE, H_/TILE, NSLICE);
    k_raster<<<rg, dim3(256,1,1), 0, stream>>>(rec, keys, Fn);
    k_post<<<(H_*W_)/4, 256, 0, stream>>>(keys, rec, features, faces, (float*)d_out);
}